// Round 2
// baseline (725.382 us; speedup 1.0000x reference)
//
#include <hip/hip_runtime.h>

#define N_NODES 20000
#define N_EDGES 160000
#define CH      768
#define CH3     2304
#define NGRAPH  256
#define NCLS    32

typedef __bf16 bf16v8 __attribute__((ext_vector_type(8)));
typedef float  f32x4  __attribute__((ext_vector_type(4)));

// ---------- helpers ----------
__device__ __forceinline__ float b2f(ushort u) {
    union { float f; unsigned u; } x; x.u = ((unsigned)u) << 16; return x.f;
}
__device__ __forceinline__ ushort f2b(float f) {
    union { float f; unsigned u; } x; x.f = f;
    unsigned r = x.u + 0x7FFFu + ((x.u >> 16) & 1u);
    return (ushort)(r >> 16);
}
__device__ __forceinline__ void load12(const ushort* __restrict__ p, float* o) {
    const ushort4* q = (const ushort4*)p;   // lane*12 ushorts = 24B -> 8B aligned
    ushort4 a = q[0], b = q[1], c = q[2];
    o[0]=b2f(a.x); o[1]=b2f(a.y); o[2]=b2f(a.z); o[3]=b2f(a.w);
    o[4]=b2f(b.x); o[5]=b2f(b.y); o[6]=b2f(b.z); o[7]=b2f(b.w);
    o[8]=b2f(c.x); o[9]=b2f(c.y); o[10]=b2f(c.z); o[11]=b2f(c.w);
}
__device__ __forceinline__ void load12f(const float* __restrict__ p, float* o) {
    const float4* q = (const float4*)p;     // lane*12 floats = 48B -> 16B aligned
    float4 a = q[0], b = q[1], c = q[2];
    o[0]=a.x; o[1]=a.y; o[2]=a.z; o[3]=a.w;
    o[4]=b.x; o[5]=b.y; o[6]=b.z; o[7]=b.w;
    o[8]=c.x; o[9]=c.y; o[10]=c.z; o[11]=c.w;
}
__device__ __forceinline__ void async_copy16(void* lds, const void* gp) {
    __builtin_amdgcn_global_load_lds((const void __attribute__((address_space(1)))*)gp,
                                     (void __attribute__((address_space(3)))*)lds, 16, 0, 0);
}

// ---------- f32 -> bf16 conversion (4-wide) ----------
__global__ void cvt_x_kernel(const float* __restrict__ src, ushort* __restrict__ dst, int n4) {
    int i = blockIdx.x * 256 + threadIdx.x;
    if (i >= n4) return;
    float4 v = ((const float4*)src)[i];
    ushort4 o; o.x = f2b(v.x); o.y = f2b(v.y); o.z = f2b(v.z); o.w = f2b(v.w);
    ((ushort4*)dst)[i] = o;
}

// ---------- all 7 weight transposes (+cvt) in one dispatch: grid (24,24,7) ----------
__global__ void transpose_cvt_all(const float* __restrict__ w_in,
                                  const float* __restrict__ Wl,
                                  const float* __restrict__ Wr,
                                  ushort* __restrict__ wt_in,
                                  ushort* __restrict__ wt_l) {
    __shared__ float tile[32][33];
    int z = blockIdx.z;
    const float* in;
    ushort* out;
    if (z == 0) { in = w_in; out = wt_in; }
    else {
        int l = (z - 1) >> 1, isr = (z - 1) & 1;
        in  = (isr ? Wr : Wl) + (size_t)l * CH * CH;
        out = wt_l + (size_t)l * 1536 * CH + (size_t)isr * CH * CH;
    }
    int bx = blockIdx.x * 32, by = blockIdx.y * 32;
    int tx = threadIdx.x, ty = threadIdx.y;
    #pragma unroll
    for (int i = ty; i < 32; i += 8) tile[i][tx] = in[(size_t)(by + i) * CH + bx + tx];
    __syncthreads();
    #pragma unroll
    for (int i = ty; i < 32; i += 8) out[(size_t)(bx + i) * CH + by + tx] = f2b(tile[tx][i]);
}

// ---------- CSR build ----------
__global__ void count_both_kernel(const int* __restrict__ dst, int* __restrict__ deg, int e,
                                  const int* __restrict__ batch, int* __restrict__ gcount, int n) {
    int i = blockIdx.x * 256 + threadIdx.x;
    if (i < e) atomicAdd(&deg[dst[i]], 1);
    if (i < n) { atomicAdd(&deg[i], 1); atomicAdd(&gcount[batch[i]], 1); }
}
__global__ __launch_bounds__(1024) void scan_kernel(const int* __restrict__ deg,
                                                    int* __restrict__ rowptr, int n) {
    __shared__ int part[1024];
    int t = threadIdx.x;
    const int chunk = (n + 1023) / 1024;
    int base = t * chunk;
    int s = 0;
    for (int i = 0; i < chunk; ++i) { int idx = base + i; if (idx < n) s += deg[idx]; }
    part[t] = s; __syncthreads();
    for (int off = 1; off < 1024; off <<= 1) {
        int v = (t >= off) ? part[t - off] : 0;
        __syncthreads();
        part[t] += v;
        __syncthreads();
    }
    int run = (t == 0) ? 0 : part[t - 1];
    for (int i = 0; i < chunk; ++i) {
        int idx = base + i;
        if (idx < n) { rowptr[idx] = run; run += deg[idx]; }
    }
    if (t == 1023) rowptr[n] = part[1023];
}
__global__ void selfloop_kernel(const int* __restrict__ rowptr, int* __restrict__ csrc,
                                int* __restrict__ cursor, int n) {
    int i = blockIdx.x * 256 + threadIdx.x;
    if (i < n) { int p = rowptr[i]; csrc[p] = i; cursor[i] = p + 1; }
}
__global__ void scatter_kernel(const int* __restrict__ src, const int* __restrict__ dst,
                               int* __restrict__ cursor, int* __restrict__ csrc, int e) {
    int i = blockIdx.x * 256 + threadIdx.x;
    if (i < e) { int p = atomicAdd(&cursor[dst[i]], 1); csrc[p] = src[i]; }
}
__global__ __launch_bounds__(256) void gscan_kernel(const int* __restrict__ gcount,
                                                    int* __restrict__ gstart) {
    __shared__ int p[256];
    int t = threadIdx.x;
    p[t] = gcount[t]; __syncthreads();
    for (int off = 1; off < 256; off <<= 1) {
        int v = (t >= off) ? p[t - off] : 0;
        __syncthreads();
        p[t] += v;
        __syncthreads();
    }
    gstart[t] = p[t] - gcount[t];
    if (t == 255) gstart[256] = p[255];
}

// ---------- GEMM: C[M,Ncols] = A[M,768] * Bt^T + bias(f32), bf16 in, fp32 accum ----------
// R2: T3+T4 counted-vmcnt pipeline (the only lever with measured effect in the
// latency-bound regime; R1 proved T2-alone is null at 2-phase). 256x256 tile,
// BK=32, 8 waves (2M x 4N), 512 thr, FOUR LDS buffers (128 KiB): while tile t
// computes from buf[t&3], tile t+3 stages into buf[(t+3)&3]. Per K-tile 2
// phases: {ds_read(8) | stageA(t+3)} bar lgkm0 16MFMA bar; {ds_read(4) |
// stageB(t+3)} bar lgkm0 16MFMA vmcnt(8) bar. vmcnt NEVER drains to 0 in the
// main loop: the counted 8 leaves tiles t+2,t+3 (2 half-stages each) in flight
// while guaranteeing tile t+1 landed (epilogue drains 8->4->0). LDS swizzle:
// 16B-slot ^= (row>>1)&3, applied as inverse-swizzled GLOBAL source + swizzled
// ds_read (rule #21; R1 measured 0 bank conflicts with this exact involution).
// T5 setprio wraps each MFMA cluster (pays only with phase role-split: m218b).
__global__ __launch_bounds__(512, 2) void gemm8_bf16_kernel(
    const ushort* __restrict__ A, int lda,
    const ushort* __restrict__ Bt,
    const float* __restrict__ biasA, const float* __restrict__ biasB, int nsplit,
    ushort* __restrict__ C, int ldc, int M, int ncolt) {
    __shared__ __bf16 As[4][256 * 32];   // 64 KiB
    __shared__ __bf16 Bs[4][256 * 32];   // 64 KiB
    int tid = threadIdx.x;
    int wid = tid >> 6, lane = tid & 63;
    int wm = wid >> 2, wn = wid & 3;
    int l16 = lane & 15, lq = lane >> 4;

    // XCD-bijective block swizzle (m204 variant; nwg not multiple of 8)
    int nwg = gridDim.x, bid = blockIdx.x;
    int q = nwg >> 3, rm = nwg & 7;
    int xcd = bid & 7, idx = bid >> 3;
    int wg = (xcd < rm ? xcd * (q + 1) : rm * (q + 1) + (xcd - rm) * q) + idx;
    int row_t = wg / ncolt, col_t = wg - row_t * ncolt;
    int row0 = row_t * 256, col0 = col_t * 256;

    // staging: round qd in {0,1}: slot s = qd*512+tid; LDS row r=s>>2, 16B slot
    // s&3. Global k-chunk pre-swizzled so LDS holds chunk (s&3)^((r>>1)&3).
    int s1 = 512 + tid;
    int r0 = tid >> 2, r1 = s1 >> 2;
    int ac0 = ((tid & 3) ^ ((tid >> 3) & 3)) * 8;
    int ac1 = ((s1 & 3) ^ ((s1 >> 3) & 3)) * 8;
    const ushort* pa0 = A + (size_t)min(row0 + r0, M - 1) * lda + ac0;
    const ushort* pa1 = A + (size_t)min(row0 + r1, M - 1) * lda + ac1;
    const ushort* pb0 = Bt + (size_t)(col0 + r0) * CH + ac0;
    const ushort* pb1 = Bt + (size_t)(col0 + r1) * CH + ac1;
    int wb0 = (wid * 64) * 8, wb1 = (512 + wid * 64) * 8;  // wave-uniform LDS dests

    // read-side swizzle: elem = row*32 + (lq ^ ((row>>1)&3))*8; for rows
    // row = 16k + l16 the swizzle term reduces to (l16>>1)&3 (k*16 is 0 mod 4)
    int koffE = (lq ^ ((l16 >> 1) & 3)) * 8;

    f32x4 acc[8][4] = {};

    #define STAGE_A(buf, t) do { int k0 = (t) * 32;                   \
        async_copy16(&As[buf][wb0], pa0 + k0);                        \
        async_copy16(&As[buf][wb1], pa1 + k0); } while (0)
    #define STAGE_B(buf, t) do { int k0 = (t) * 32;                   \
        async_copy16(&Bs[buf][wb0], pb0 + k0);                        \
        async_copy16(&Bs[buf][wb1], pb1 + k0); } while (0)

    // prologue: stage tiles 0,1,2 (12 loads); wait oldest 4 (= tile 0)
    STAGE_A(0, 0); STAGE_B(0, 0);
    STAGE_A(1, 1); STAGE_B(1, 1);
    STAGE_A(2, 2); STAGE_B(2, 2);
    asm volatile("s_waitcnt vmcnt(8)" ::: "memory");
    __builtin_amdgcn_s_barrier();

    for (int t = 0; t < 24; ++t) {
        int buf = t & 3, sbuf = (t + 3) & 3;
        const __bf16* Ab = &As[buf][(wm * 128 + l16) * 32 + koffE];
        const __bf16* Bb = &Bs[buf][(wn * 64 + l16) * 32 + koffE];
        bf16v8 av[4], bv[4];
        // ---- phase 0: rows [wm*128 .. +63], all 4 col-frags ----
        #pragma unroll
        for (int f = 0; f < 4; ++f) av[f] = *(const bf16v8*)(Ab + f * 16 * 32);
        #pragma unroll
        for (int g = 0; g < 4; ++g) bv[g] = *(const bf16v8*)(Bb + g * 16 * 32);
        if (t < 21) STAGE_A(sbuf, t + 3);
        __builtin_amdgcn_s_barrier();
        asm volatile("s_waitcnt lgkmcnt(0)" ::: "memory");
        __builtin_amdgcn_sched_barrier(0);
        __builtin_amdgcn_s_setprio(1);
        #pragma unroll
        for (int f = 0; f < 4; ++f)
            #pragma unroll
            for (int g = 0; g < 4; ++g)
                acc[f][g] = __builtin_amdgcn_mfma_f32_16x16x32_bf16(av[f], bv[g], acc[f][g], 0, 0, 0);
        __builtin_amdgcn_s_setprio(0);
        __builtin_amdgcn_s_barrier();
        // ---- phase 1: rows [wm*128+64 .. +127], bv reused ----
        #pragma unroll
        for (int f = 0; f < 4; ++f) av[f] = *(const bf16v8*)(Ab + (64 + f * 16) * 32);
        if (t < 21) STAGE_B(sbuf, t + 3);
        __builtin_amdgcn_s_barrier();
        asm volatile("s_waitcnt lgkmcnt(0)" ::: "memory");
        __builtin_amdgcn_sched_barrier(0);
        __builtin_amdgcn_s_setprio(1);
        #pragma unroll
        for (int f = 0; f < 4; ++f)
            #pragma unroll
            for (int g = 0; g < 4; ++g)
                acc[4 + f][g] = __builtin_amdgcn_mfma_f32_16x16x32_bf16(av[f], bv[g], acc[4 + f][g], 0, 0, 0);
        __builtin_amdgcn_s_setprio(0);
        // counted drain: tile t+1 guaranteed landed; tiles t+2,t+3 stay in flight
        if (t < 21)       { asm volatile("s_waitcnt vmcnt(8)" ::: "memory"); }
        else if (t == 21) { asm volatile("s_waitcnt vmcnt(4)" ::: "memory"); }
        else if (t == 22) { asm volatile("s_waitcnt vmcnt(0)" ::: "memory"); }
        __builtin_amdgcn_s_barrier();
    }
    #undef STAGE_A
    #undef STAGE_B

    float bias[4];
    #pragma unroll
    for (int g = 0; g < 4; ++g) {
        int col = col0 + wn * 64 + g * 16 + l16;
        bias[g] = (col < nsplit) ? biasA[col] : biasB[col - nsplit];
    }
    #pragma unroll
    for (int f = 0; f < 8; ++f) {
        int mbase = row0 + wm * 128 + f * 16 + lq * 4;
        #pragma unroll
        for (int g = 0; g < 4; ++g) {
            int col = col0 + wn * 64 + g * 16 + l16;
            #pragma unroll
            for (int r = 0; r < 4; ++r) {
                int mm = mbase + r;
                if (mm < M) C[(size_t)mm * ldc + col] = f2b(acc[f][g][r] + bias[g]);
            }
        }
    }
}

// ---------- fused GATv2 node kernel. ONE wave per node (12 ch/lane), NO-MAX
// softmax (logits are LN-bounded, |logit| <~ 8 -> exp safe un-shifted; softmax
// is shift-invariant so result is identical up to rounding). Loop-carried work
// is pure fma accumulation; dual chains kept only for load-level parallelism.
__global__ __launch_bounds__(256) void gat_node_kernel(
    const ushort* __restrict__ xlxr,          // [N][1536] bf16: xl | xr
    const ushort* __restrict__ hin, int ldh,  // residual rows (bf16)
    const int* __restrict__ rowptr, const int* __restrict__ csrc,
    const float* __restrict__ att, const float* __restrict__ gbias,
    const float* __restrict__ lnw, const float* __restrict__ lnb,
    ushort* __restrict__ hout, int nn) {
    int wv = threadIdx.x >> 6, lane = threadIdx.x & 63;
    int n = blockIdx.x * 4 + wv;     // grid exactly nn/4
    int c0 = lane * 12;
    const ushort* __restrict__ xbase = xlxr + c0;
    float attv[12], xr[12], acc1[12] = {}, acc2[12] = {};
    load12f(att + c0, attv);
    load12(xbase + (size_t)n * 1536 + CH, xr);
    float s1 = 0.f, s2 = 0.f;
    int rs = rowptr[n], re = rowptr[n + 1];
    int e = rs;
    for (; e + 1 < re; e += 2) {
        int sa = csrc[e], sb = csrc[e + 1];
        float xa[12], xb[12];
        load12(xbase + (size_t)sa * 1536, xa);
        load12(xbase + (size_t)sb * 1536, xb);
        float da = 0.f, db = 0.f;
        #pragma unroll
        for (int j = 0; j < 12; ++j) {
            float va = xa[j] + xr[j]; va = fmaxf(va, 0.2f * va);
            float vb = xb[j] + xr[j]; vb = fmaxf(vb, 0.2f * vb);
            da = fmaf(va, attv[j], da);
            db = fmaf(vb, attv[j], db);
        }
        da += __shfl_xor(da, 1); db += __shfl_xor(db, 1);
        da += __shfl_xor(da, 2); db += __shfl_xor(db, 2);
        da += __shfl_xor(da, 4); db += __shfl_xor(db, 4);   // 8-lane head logits
        float ea = __expf(da), eb = __expf(db);
        s1 += ea; s2 += eb;
        #pragma unroll
        for (int j = 0; j < 12; ++j) {
            acc1[j] = fmaf(ea, xa[j], acc1[j]);
            acc2[j] = fmaf(eb, xb[j], acc2[j]);
        }
    }
    if (e < re) {   // odd tail -> chain 1
        int sa = csrc[e];
        float xa[12];
        load12(xbase + (size_t)sa * 1536, xa);
        float da = 0.f;
        #pragma unroll
        for (int j = 0; j < 12; ++j) {
            float va = xa[j] + xr[j]; va = fmaxf(va, 0.2f * va);
            da = fmaf(va, attv[j], da);
        }
        da += __shfl_xor(da, 1);
        da += __shfl_xor(da, 2);
        da += __shfl_xor(da, 4);
        float ea = __expf(da);
        s1 += ea;
        #pragma unroll
        for (int j = 0; j < 12; ++j) acc1[j] = fmaf(ea, xa[j], acc1[j]);
    }
    float inv = 1.f / (s1 + s2);
    float hres[12], gb[12], tv[12];
    load12(hin + (size_t)n * ldh + c0, hres);
    load12f(gbias + c0, gb);
    float lsum = 0.f, lsq = 0.f;
    #pragma unroll
    for (int j = 0; j < 12; ++j) {
        tv[j] = (acc1[j] + acc2[j]) * inv + gb[j] + hres[j];
        lsum += tv[j];
        lsq = fmaf(tv[j], tv[j], lsq);
    }
    #pragma unroll
    for (int o = 1; o < 64; o <<= 1) { lsum += __shfl_xor(lsum, o); lsq += __shfl_xor(lsq, o); }
    float mu = lsum * (1.f / 768.f);
    float var = lsq * (1.f / 768.f) - mu * mu;
    float rstd = rsqrtf(var + 1e-5f);
    float wv12[12], bv12[12];
    load12f(lnw + c0, wv12);
    load12f(lnb + c0, bv12);
    ushort* op = hout + (size_t)n * CH3 + c0;
    ushort4 u[3];
    #pragma unroll
    for (int k = 0; k < 3; ++k) {
        float g[4];
        #pragma unroll
        for (int q = 0; q < 4; ++q) {
            int j = k * 4 + q;
            float y = (tv[j] - mu) * rstd * wv12[j] + bv12[j];
            g[q] = 0.5f * y * (1.f + erff(y * 0.70710678118f));
        }
        u[k].x = f2b(g[0]); u[k].y = f2b(g[1]); u[k].z = f2b(g[2]); u[k].w = f2b(g[3]);
        ((ushort4*)op)[k] = u[k];
    }
}

// ---------- global mean pool: 4 independent accumulators ----------
__global__ __launch_bounds__(256) void pool_kernel(const ushort* __restrict__ hc,
                                                   const int* __restrict__ gstart,
                                                   float* __restrict__ pooled) {
    int g = blockIdx.x;
    int c = blockIdx.y * 256 + threadIdx.x;
    int s = gstart[g], e = gstart[g + 1];
    const ushort* p = hc + (size_t)s * CH3 + c;
    float a0 = 0.f, a1 = 0.f, a2 = 0.f, a3 = 0.f;
    int n = s;
    for (; n + 3 < e; n += 4) {
        a0 += b2f(p[0]);
        a1 += b2f(p[CH3]);
        a2 += b2f(p[2 * CH3]);
        a3 += b2f(p[3 * CH3]);
        p += 4 * CH3;
    }
    for (; n < e; ++n) { a0 += b2f(*p); p += CH3; }
    float a = (a0 + a1) + (a2 + a3);
    pooled[(size_t)g * CH3 + c] = a * (1.f / (float)max(e - s, 1));
}

// ---------- final LN + [2304x32] matmul (all f32) ----------
__global__ __launch_bounds__(256) void head_kernel(const float* __restrict__ pooled,
                                                   const float* __restrict__ olnw,
                                                   const float* __restrict__ olnb,
                                                   const float* __restrict__ wout,
                                                   const float* __restrict__ bout,
                                                   float* __restrict__ outp) {
    __shared__ float row[CH3];
    __shared__ float red[8];
    __shared__ float parts[8][32];
    int g = blockIdx.x, t = threadIdx.x;
    int lane = t & 63, wv = t >> 6;
    float s = 0.f;
    for (int c = t; c < CH3; c += 256) { float v = pooled[(size_t)g * CH3 + c]; row[c] = v; s += v; }
    #pragma unroll
    for (int o = 1; o < 64; o <<= 1) s += __shfl_xor(s, o);
    if (lane == 0) red[wv] = s;
    __syncthreads();
    float mu = (red[0] + red[1] + red[2] + red[3]) * (1.f / (float)CH3);
    float q = 0.f;
    for (int c = t; c < CH3; c += 256) { float d = row[c] - mu; q += d * d; }
    #pragma unroll
    for (int o = 1; o < 64; o <<= 1) q += __shfl_xor(q, o);
    if (lane == 0) red[4 + wv] = q;
    __syncthreads();
    float rstd = rsqrtf((red[4] + red[5] + red[6] + red[7]) * (1.f / (float)CH3) + 1e-5f);
    for (int c = t; c < CH3; c += 256)
        row[c] = (row[c] - mu) * rstd * olnw[c] + olnb[c];
    __syncthreads();
    int j = t & 31, slice = t >> 5;
    float a = 0.f;
    int cb = slice * (CH3 / 8);
    for (int c = cb; c < cb + CH3 / 8; ++c) a += row[c] * wout[(size_t)c * 32 + j];
    parts[slice][j] = a;
    __syncthreads();
    if (t < 32) {
        float r = bout[t];
        #pragma unroll
        for (int si = 0; si < 8; ++si) r += parts[si][t];
        outp[(size_t)g * 32 + t] = r;
    }
}

// ---------- launch ----------
extern "C" void kernel_launch(void* const* d_in, const int* in_sizes, int n_in,
                              void* d_out, int out_size, void* d_ws, size_t ws_size,
                              hipStream_t stream) {
    const float* x     = (const float*)d_in[0];
    const int*   ei    = (const int*)d_in[1];     // [2][E] int32
    const int*   batch = (const int*)d_in[2];
    const float* w_in  = (const float*)d_in[3];
    const float* b_in  = (const float*)d_in[4];
    const float* Wl    = (const float*)d_in[5];
    const float* bl    = (const float*)d_in[6];
    const float* Wr    = (const float*)d_in[7];
    const float* br    = (const float*)d_in[8];
    const float* att   = (const float*)d_in[9];
    const float* gbias = (const float*)d_in[10];
    const float* lnw   = (const float*)d_in[11];
    const float* lnb   = (const float*)d_in[12];
    const float* olnw  = (const float*)d_in[13];
    const float* olnb  = (const float*)d_in[14];
    const float* wout  = (const float*)d_in[15];
    const float* bout  = (const float*)d_in[16];

    char* ws = (char*)d_ws;
    size_t off = 0;
    auto alloc = [&](size_t bytes) -> void* {
        void* p = ws + off;
        off = (off + bytes + 255) & ~(size_t)255;
        return p;
    };
    ushort* h0     = (ushort*)alloc((size_t)N_NODES * CH * 2);
    ushort* hc     = (ushort*)alloc((size_t)N_NODES * CH3 * 2);
    ushort* xlxr   = (ushort*)alloc((size_t)N_NODES * 1536 * 2);
    ushort* wt_in  = (ushort*)alloc((size_t)CH * CH * 2);
    ushort* wt_l   = (ushort*)alloc((size_t)3 * 1536 * CH * 2);
    int*    deg    = (int*)alloc((size_t)N_NODES * 4);
    int*    rowptr = (int*)alloc((size_t)(N_NODES + 1) * 4);
    int*    cursor = (int*)alloc((size_t)N_NODES * 4);
    int*    csrc   = (int*)alloc((size_t)(N_EDGES + N_NODES) * 4);
    int*    gcount = (int*)alloc(256 * 4);
    int*    gstart = (int*)alloc(257 * 4);
    float*  pooled = (float*)alloc((size_t)NGRAPH * CH3 * 4);
    if (off > ws_size) return;

    // bf16 copy of x aliases hc (x is consumed by the h0-GEMM before hc's first write)
    ushort* xc = hc;

    // 1) convert x to bf16; all 7 weight transposes in one dispatch
    cvt_x_kernel<<<(N_NODES * CH / 4 + 255) / 256, 256, 0, stream>>>(x, xc, N_NODES * CH / 4);
    transpose_cvt_all<<<dim3(24, 24, 7), dim3(32, 8), 0, stream>>>(w_in, Wl, Wr, wt_in, wt_l);

    // 2) CSR by dst + graph segments
    int nb = (N_NODES + 255) / 256, eb = (N_EDGES + 255) / 256;
    hipMemsetAsync(deg, 0, (size_t)N_NODES * 4, stream);
    hipMemsetAsync(gcount, 0, 256 * 4, stream);
    count_both_kernel<<<eb, 256, 0, stream>>>(ei + N_EDGES, deg, N_EDGES, batch, gcount, N_NODES);
    scan_kernel<<<1, 1024, 0, stream>>>(deg, rowptr, N_NODES);
    selfloop_kernel<<<nb, 256, 0, stream>>>(rowptr, csrc, cursor, N_NODES);
    scatter_kernel<<<eb, 256, 0, stream>>>(ei, ei + N_EDGES, cursor, csrc, N_EDGES);
    gscan_kernel<<<1, 256, 0, stream>>>(gcount, gstart);

    // 3) h0 = x @ w_in + b_in  (79 row-tiles x 3 col-tiles of 256)
    gemm8_bf16_kernel<<<79 * 3, 512, 0, stream>>>(
        xc, CH, wt_in, b_in, b_in, CH, h0, CH, N_NODES, 3);

    // 4) three GATv2 layers (79 x 6 col-tiles)
    for (int l = 0; l < 3; ++l) {
        const ushort* hprev = (l == 0) ? h0 : (hc + (size_t)(l - 1) * CH);
        int ldh = (l == 0) ? CH : CH3;
        gemm8_bf16_kernel<<<79 * 6, 512, 0, stream>>>(
            hprev, ldh, wt_l + (size_t)l * 1536 * CH,
            bl + (size_t)l * CH, br + (size_t)l * CH, CH,
            xlxr, 1536, N_NODES, 6);
        gat_node_kernel<<<N_NODES / 4, 256, 0, stream>>>(
            xlxr, hprev, ldh, rowptr, csrc,
            att + (size_t)l * CH, gbias + (size_t)l * CH,
            lnw + (size_t)l * CH, lnb + (size_t)l * CH,
            hc + (size_t)l * CH, N_NODES);
    }

    // 5) pool + head (all f32, f32 output)
    pool_kernel<<<dim3(NGRAPH, CH3 / 256), 256, 0, stream>>>(hc, gstart, pooled);
    head_kernel<<<NGRAPH, 256, 0, stream>>>(pooled, olnw, olnb, wout, bout, (float*)d_out);
}

// Round 3
// 673.096 us; speedup vs baseline: 1.0777x; 1.0777x over previous
//
#include <hip/hip_runtime.h>

#define N_NODES 20000
#define N_EDGES 160000
#define CH      768
#define CH3     2304
#define NGRAPH  256
#define NCLS    32

typedef __bf16 bf16v8 __attribute__((ext_vector_type(8)));
typedef float  f32x4  __attribute__((ext_vector_type(4)));

// ---------- helpers ----------
__device__ __forceinline__ float b2f(ushort u) {
    union { float f; unsigned u; } x; x.u = ((unsigned)u) << 16; return x.f;
}
__device__ __forceinline__ ushort f2b(float f) {
    union { float f; unsigned u; } x; x.f = f;
    unsigned r = x.u + 0x7FFFu + ((x.u >> 16) & 1u);
    return (ushort)(r >> 16);
}
__device__ __forceinline__ void load12(const ushort* __restrict__ p, float* o) {
    const ushort4* q = (const ushort4*)p;   // lane*12 ushorts = 24B -> 8B aligned
    ushort4 a = q[0], b = q[1], c = q[2];
    o[0]=b2f(a.x); o[1]=b2f(a.y); o[2]=b2f(a.z); o[3]=b2f(a.w);
    o[4]=b2f(b.x); o[5]=b2f(b.y); o[6]=b2f(b.z); o[7]=b2f(b.w);
    o[8]=b2f(c.x); o[9]=b2f(c.y); o[10]=b2f(c.z); o[11]=b2f(c.w);
}
__device__ __forceinline__ void load12f(const float* __restrict__ p, float* o) {
    const float4* q = (const float4*)p;     // lane*12 floats = 48B -> 16B aligned
    float4 a = q[0], b = q[1], c = q[2];
    o[0]=a.x; o[1]=a.y; o[2]=a.z; o[3]=a.w;
    o[4]=b.x; o[5]=b.y; o[6]=b.z; o[7]=b.w;
    o[8]=c.x; o[9]=c.y; o[10]=c.z; o[11]=c.w;
}
__device__ __forceinline__ void async_copy16(void* lds, const void* gp) {
    __builtin_amdgcn_global_load_lds((const void __attribute__((address_space(1)))*)gp,
                                     (void __attribute__((address_space(3)))*)lds, 16, 0, 0);
}

// ---------- f32 -> bf16 conversion (4-wide) ----------
__global__ void cvt_x_kernel(const float* __restrict__ src, ushort* __restrict__ dst, int n4) {
    int i = blockIdx.x * 256 + threadIdx.x;
    if (i >= n4) return;
    float4 v = ((const float4*)src)[i];
    ushort4 o; o.x = f2b(v.x); o.y = f2b(v.y); o.z = f2b(v.z); o.w = f2b(v.w);
    ((ushort4*)dst)[i] = o;
}

// ---------- all 7 weight transposes (+cvt) in one dispatch: grid (24,24,7) ----------
__global__ void transpose_cvt_all(const float* __restrict__ w_in,
                                  const float* __restrict__ Wl,
                                  const float* __restrict__ Wr,
                                  ushort* __restrict__ wt_in,
                                  ushort* __restrict__ wt_l) {
    __shared__ float tile[32][33];
    int z = blockIdx.z;
    const float* in;
    ushort* out;
    if (z == 0) { in = w_in; out = wt_in; }
    else {
        int l = (z - 1) >> 1, isr = (z - 1) & 1;
        in  = (isr ? Wr : Wl) + (size_t)l * CH * CH;
        out = wt_l + (size_t)l * 1536 * CH + (size_t)isr * CH * CH;
    }
    int bx = blockIdx.x * 32, by = blockIdx.y * 32;
    int tx = threadIdx.x, ty = threadIdx.y;
    #pragma unroll
    for (int i = ty; i < 32; i += 8) tile[i][tx] = in[(size_t)(by + i) * CH + bx + tx];
    __syncthreads();
    #pragma unroll
    for (int i = ty; i < 32; i += 8) out[(size_t)(bx + i) * CH + by + tx] = f2b(tile[tx][i]);
}

// ---------- CSR build ----------
__global__ void count_both_kernel(const int* __restrict__ dst, int* __restrict__ deg, int e,
                                  const int* __restrict__ batch, int* __restrict__ gcount, int n) {
    int i = blockIdx.x * 256 + threadIdx.x;
    if (i < e) atomicAdd(&deg[dst[i]], 1);
    if (i < n) { atomicAdd(&deg[i], 1); atomicAdd(&gcount[batch[i]], 1); }
}
__global__ __launch_bounds__(1024) void scan_kernel(const int* __restrict__ deg,
                                                    int* __restrict__ rowptr, int n) {
    __shared__ int part[1024];
    int t = threadIdx.x;
    const int chunk = (n + 1023) / 1024;
    int base = t * chunk;
    int s = 0;
    for (int i = 0; i < chunk; ++i) { int idx = base + i; if (idx < n) s += deg[idx]; }
    part[t] = s; __syncthreads();
    for (int off = 1; off < 1024; off <<= 1) {
        int v = (t >= off) ? part[t - off] : 0;
        __syncthreads();
        part[t] += v;
        __syncthreads();
    }
    int run = (t == 0) ? 0 : part[t - 1];
    for (int i = 0; i < chunk; ++i) {
        int idx = base + i;
        if (idx < n) { rowptr[idx] = run; run += deg[idx]; }
    }
    if (t == 1023) rowptr[n] = part[1023];
}
__global__ void selfloop_kernel(const int* __restrict__ rowptr, int* __restrict__ csrc,
                                int* __restrict__ cursor, int n) {
    int i = blockIdx.x * 256 + threadIdx.x;
    if (i < n) { int p = rowptr[i]; csrc[p] = i; cursor[i] = p + 1; }
}
__global__ void scatter_kernel(const int* __restrict__ src, const int* __restrict__ dst,
                               int* __restrict__ cursor, int* __restrict__ csrc, int e) {
    int i = blockIdx.x * 256 + threadIdx.x;
    if (i < e) { int p = atomicAdd(&cursor[dst[i]], 1); csrc[p] = src[i]; }
}
__global__ __launch_bounds__(256) void gscan_kernel(const int* __restrict__ gcount,
                                                    int* __restrict__ gstart) {
    __shared__ int p[256];
    int t = threadIdx.x;
    p[t] = gcount[t]; __syncthreads();
    for (int off = 1; off < 256; off <<= 1) {
        int v = (t >= off) ? p[t - off] : 0;
        __syncthreads();
        p[t] += v;
        __syncthreads();
    }
    gstart[t] = p[t] - gcount[t];
    if (t == 255) gstart[256] = p[255];
}

// ---------- GEMM: C[M,Ncols] = A[M,768] * Bt^T + bias(f32), bf16 in, fp32 accum ----------
// R3 theory: R0/R1/R2 (three different schedules) all landed at ~88us / 21%
// MfmaUtil -> the invariant cost is the 4 block-wide barrier rendezvous +
// bulk-lgkm drains per K-tile(32), not the staging pipeline. This version:
// BK=64, 2 buffers (same 128KB LDS), ONE vmcnt(0)+s_barrier per K-tile(64)
// (= 0.5 barriers per K=32, 8x fewer than R2). All 8 staging loads for tile
// t+1 issue at the START of tile t (~1500+cyc of MFMA/ds_read slack before the
// boundary wait -> the drain costs ~0). No mid-tile barriers, no manual bulk
// lgkmcnt(0): compiler emits counted lgkmcnt, interleaving ds_read with MFMA,
// and un-barriered waves drift so one wave's LDS drain overlaps another's MFMA.
// Cross-wave staging hazard proof: tile t's gloads write buf[(t+1)&1], whose
// previous readers (tile t-1) drained before the t-1 boundary barrier; data
// for tile t's reads (staged at t-1 start) is guaranteed by the t-1 boundary
// vmcnt(0)+barrier (each wave drains its own gloads; barrier publishes).
// LDS swizzle (rule #21, both-sides involution): row R, 16B-chunk c holds
// global chunk c ^ (R&7); reads at chunk (4*ks+lq) ^ (l16&7). Octet lanes
// land on 8 distinct 16B columns -> conflict-free (R1 measured 0 with the
// BK=32 variant of this family).
__global__ __launch_bounds__(512, 2) void gemm8_bf16_kernel(
    const ushort* __restrict__ A, int lda,
    const ushort* __restrict__ Bt,
    const float* __restrict__ biasA, const float* __restrict__ biasB, int nsplit,
    ushort* __restrict__ C, int ldc, int M, int ncolt) {
    __shared__ __align__(16) __bf16 As[2][256 * 64];   // 64 KiB
    __shared__ __align__(16) __bf16 Bs[2][256 * 64];   // 64 KiB
    int tid = threadIdx.x;
    int wid = tid >> 6, lane = tid & 63;
    int wm = wid >> 2, wn = wid & 3;
    int l16 = lane & 15, lq = lane >> 4;

    // XCD-bijective block swizzle (m204 variant)
    int nwg = gridDim.x, bid = blockIdx.x;
    int q = nwg >> 3, rm = nwg & 7;
    int xcd = bid & 7, idx = bid >> 3;
    int wg = (xcd < rm ? xcd * (q + 1) : rm * (q + 1) + (xcd - rm) * q) + idx;
    int row_t = wg / ncolt, col_t = wg - row_t * ncolt;
    int row0 = row_t * 256, col0 = col_t * 256;

    // ---- staging map: round r (0..3), slot = r*512+tid -> row r*64+(tid>>3),
    // 16B chunk tid&7. Global chunk = (tid&7) ^ ((tid>>3)&7)  (involution).
    int ak = (((tid & 7) ^ ((tid >> 3) & 7)) << 3);
    const ushort* gA[4];
    const ushort* gB[4];
    #pragma unroll
    for (int r = 0; r < 4; ++r) {
        int ra = min(row0 + r * 64 + (tid >> 3), M - 1);
        gA[r] = A + (size_t)ra * lda + ak;
        gB[r] = Bt + (size_t)(col0 + r * 64 + (tid >> 3)) * CH + ak;
    }
    int ldst = wid << 9;   // wave-uniform LDS elem base within a round block

    // ---- read map: row*64 + ((ks*4+lq)^(l16&7))*8
    int swz = l16 & 7;
    int arow = wm * 128 + l16;
    int brow = wn * 64 + l16;
    int kc0 = ((lq ^ swz) << 3);
    int kc1 = (((4 + lq) ^ swz) << 3);

    f32x4 acc[8][4] = {};

    #define STAGE(buf, kof) do { _Pragma("unroll")                         \
        for (int r = 0; r < 4; ++r) {                                      \
            async_copy16(&As[buf][(r << 12) + ldst], gA[r] + (kof));       \
            async_copy16(&Bs[buf][(r << 12) + ldst], gB[r] + (kof));       \
        } } while (0)

    STAGE(0, 0);
    asm volatile("s_waitcnt vmcnt(0)" ::: "memory");
    __builtin_amdgcn_s_barrier();
    __builtin_amdgcn_sched_barrier(0);

    for (int t = 0; t < 12; ++t) {
        int buf = t & 1;
        if (t < 11) STAGE(buf ^ 1, (t + 1) * 64);
        __builtin_amdgcn_sched_barrier(0);
        const __bf16* Ab = &As[buf][arow * 64];
        const __bf16* Bb = &Bs[buf][brow * 64];
        bf16v8 a0[4], a1[4], b0[4], b1[4];
        #pragma unroll
        for (int g = 0; g < 4; ++g) {
            b0[g] = *(const bf16v8*)(Bb + g * 16 * 64 + kc0);
            b1[g] = *(const bf16v8*)(Bb + g * 16 * 64 + kc1);
        }
        #pragma unroll
        for (int f = 0; f < 4; ++f) {
            a0[f] = *(const bf16v8*)(Ab + f * 16 * 64 + kc0);
            a1[f] = *(const bf16v8*)(Ab + f * 16 * 64 + kc1);
        }
        __builtin_amdgcn_s_setprio(1);
        #pragma unroll
        for (int f = 0; f < 4; ++f)
            #pragma unroll
            for (int g = 0; g < 4; ++g) {
                acc[f][g] = __builtin_amdgcn_mfma_f32_16x16x32_bf16(a0[f], b0[g], acc[f][g], 0, 0, 0);
                acc[f][g] = __builtin_amdgcn_mfma_f32_16x16x32_bf16(a1[f], b1[g], acc[f][g], 0, 0, 0);
            }
        __builtin_amdgcn_s_setprio(0);
        // phase 1: rows +64, b-frags reused
        #pragma unroll
        for (int f = 0; f < 4; ++f) {
            a0[f] = *(const bf16v8*)(Ab + (64 + f * 16) * 64 + kc0);
            a1[f] = *(const bf16v8*)(Ab + (64 + f * 16) * 64 + kc1);
        }
        __builtin_amdgcn_s_setprio(1);
        #pragma unroll
        for (int f = 0; f < 4; ++f)
            #pragma unroll
            for (int g = 0; g < 4; ++g) {
                acc[4 + f][g] = __builtin_amdgcn_mfma_f32_16x16x32_bf16(a0[f], b0[g], acc[4 + f][g], 0, 0, 0);
                acc[4 + f][g] = __builtin_amdgcn_mfma_f32_16x16x32_bf16(a1[f], b1[g], acc[4 + f][g], 0, 0, 0);
            }
        __builtin_amdgcn_s_setprio(0);
        if (t < 11) {   // single boundary rendezvous per K-tile
            __builtin_amdgcn_sched_barrier(0);
            asm volatile("s_waitcnt vmcnt(0)" ::: "memory");
            __builtin_amdgcn_s_barrier();
            __builtin_amdgcn_sched_barrier(0);
        }
    }
    #undef STAGE

    float bias[4];
    #pragma unroll
    for (int g = 0; g < 4; ++g) {
        int col = col0 + wn * 64 + g * 16 + l16;
        bias[g] = (col < nsplit) ? biasA[col] : biasB[col - nsplit];
    }
    #pragma unroll
    for (int f = 0; f < 8; ++f) {
        int mbase = row0 + wm * 128 + f * 16 + lq * 4;
        #pragma unroll
        for (int g = 0; g < 4; ++g) {
            int col = col0 + wn * 64 + g * 16 + l16;
            #pragma unroll
            for (int r = 0; r < 4; ++r) {
                int mm = mbase + r;
                if (mm < M) C[(size_t)mm * ldc + col] = f2b(acc[f][g][r] + bias[g]);
            }
        }
    }
}

// ---------- fused GATv2 node kernel. ONE wave per node (12 ch/lane), NO-MAX
// softmax (logits are LN-bounded, |logit| <~ 8 -> exp safe un-shifted; softmax
// is shift-invariant so result is identical up to rounding). Loop-carried work
// is pure fma accumulation; dual chains kept only for load-level parallelism.
__global__ __launch_bounds__(256) void gat_node_kernel(
    const ushort* __restrict__ xlxr,          // [N][1536] bf16: xl | xr
    const ushort* __restrict__ hin, int ldh,  // residual rows (bf16)
    const int* __restrict__ rowptr, const int* __restrict__ csrc,
    const float* __restrict__ att, const float* __restrict__ gbias,
    const float* __restrict__ lnw, const float* __restrict__ lnb,
    ushort* __restrict__ hout, int nn) {
    int wv = threadIdx.x >> 6, lane = threadIdx.x & 63;
    int n = blockIdx.x * 4 + wv;     // grid exactly nn/4
    int c0 = lane * 12;
    const ushort* __restrict__ xbase = xlxr + c0;
    float attv[12], xr[12], acc1[12] = {}, acc2[12] = {};
    load12f(att + c0, attv);
    load12(xbase + (size_t)n * 1536 + CH, xr);
    float s1 = 0.f, s2 = 0.f;
    int rs = rowptr[n], re = rowptr[n + 1];
    int e = rs;
    for (; e + 1 < re; e += 2) {
        int sa = csrc[e], sb = csrc[e + 1];
        float xa[12], xb[12];
        load12(xbase + (size_t)sa * 1536, xa);
        load12(xbase + (size_t)sb * 1536, xb);
        float da = 0.f, db = 0.f;
        #pragma unroll
        for (int j = 0; j < 12; ++j) {
            float va = xa[j] + xr[j]; va = fmaxf(va, 0.2f * va);
            float vb = xb[j] + xr[j]; vb = fmaxf(vb, 0.2f * vb);
            da = fmaf(va, attv[j], da);
            db = fmaf(vb, attv[j], db);
        }
        da += __shfl_xor(da, 1); db += __shfl_xor(db, 1);
        da += __shfl_xor(da, 2); db += __shfl_xor(db, 2);
        da += __shfl_xor(da, 4); db += __shfl_xor(db, 4);   // 8-lane head logits
        float ea = __expf(da), eb = __expf(db);
        s1 += ea; s2 += eb;
        #pragma unroll
        for (int j = 0; j < 12; ++j) {
            acc1[j] = fmaf(ea, xa[j], acc1[j]);
            acc2[j] = fmaf(eb, xb[j], acc2[j]);
        }
    }
    if (e < re) {   // odd tail -> chain 1
        int sa = csrc[e];
        float xa[12];
        load12(xbase + (size_t)sa * 1536, xa);
        float da = 0.f;
        #pragma unroll
        for (int j = 0; j < 12; ++j) {
            float va = xa[j] + xr[j]; va = fmaxf(va, 0.2f * va);
            da = fmaf(va, attv[j], da);
        }
        da += __shfl_xor(da, 1);
        da += __shfl_xor(da, 2);
        da += __shfl_xor(da, 4);
        float ea = __expf(da);
        s1 += ea;
        #pragma unroll
        for (int j = 0; j < 12; ++j) acc1[j] = fmaf(ea, xa[j], acc1[j]);
    }
    float inv = 1.f / (s1 + s2);
    float hres[12], gb[12], tv[12];
    load12(hin + (size_t)n * ldh + c0, hres);
    load12f(gbias + c0, gb);
    float lsum = 0.f, lsq = 0.f;
    #pragma unroll
    for (int j = 0; j < 12; ++j) {
        tv[j] = (acc1[j] + acc2[j]) * inv + gb[j] + hres[j];
        lsum += tv[j];
        lsq = fmaf(tv[j], tv[j], lsq);
    }
    #pragma unroll
    for (int o = 1; o < 64; o <<= 1) { lsum += __shfl_xor(lsum, o); lsq += __shfl_xor(lsq, o); }
    float mu = lsum * (1.f / 768.f);
    float var = lsq * (1.f / 768.f) - mu * mu;
    float rstd = rsqrtf(var + 1e-5f);
    float wv12[12], bv12[12];
    load12f(lnw + c0, wv12);
    load12f(lnb + c0, bv12);
    ushort* op = hout + (size_t)n * CH3 + c0;
    ushort4 u[3];
    #pragma unroll
    for (int k = 0; k < 3; ++k) {
        float g[4];
        #pragma unroll
        for (int q = 0; q < 4; ++q) {
            int j = k * 4 + q;
            float y = (tv[j] - mu) * rstd * wv12[j] + bv12[j];
            g[q] = 0.5f * y * (1.f + erff(y * 0.70710678118f));
        }
        u[k].x = f2b(g[0]); u[k].y = f2b(g[1]); u[k].z = f2b(g[2]); u[k].w = f2b(g[3]);
        ((ushort4*)op)[k] = u[k];
    }
}

// ---------- global mean pool: 4 independent accumulators ----------
__global__ __launch_bounds__(256) void pool_kernel(const ushort* __restrict__ hc,
                                                   const int* __restrict__ gstart,
                                                   float* __restrict__ pooled) {
    int g = blockIdx.x;
    int c = blockIdx.y * 256 + threadIdx.x;
    int s = gstart[g], e = gstart[g + 1];
    const ushort* p = hc + (size_t)s * CH3 + c;
    float a0 = 0.f, a1 = 0.f, a2 = 0.f, a3 = 0.f;
    int n = s;
    for (; n + 3 < e; n += 4) {
        a0 += b2f(p[0]);
        a1 += b2f(p[CH3]);
        a2 += b2f(p[2 * CH3]);
        a3 += b2f(p[3 * CH3]);
        p += 4 * CH3;
    }
    for (; n < e; ++n) { a0 += b2f(*p); p += CH3; }
    float a = (a0 + a1) + (a2 + a3);
    pooled[(size_t)g * CH3 + c] = a * (1.f / (float)max(e - s, 1));
}

// ---------- final LN + [2304x32] matmul (all f32) ----------
__global__ __launch_bounds__(256) void head_kernel(const float* __restrict__ pooled,
                                                   const float* __restrict__ olnw,
                                                   const float* __restrict__ olnb,
                                                   const float* __restrict__ wout,
                                                   const float* __restrict__ bout,
                                                   float* __restrict__ outp) {
    __shared__ float row[CH3];
    __shared__ float red[8];
    __shared__ float parts[8][32];
    int g = blockIdx.x, t = threadIdx.x;
    int lane = t & 63, wv = t >> 6;
    float s = 0.f;
    for (int c = t; c < CH3; c += 256) { float v = pooled[(size_t)g * CH3 + c]; row[c] = v; s += v; }
    #pragma unroll
    for (int o = 1; o < 64; o <<= 1) s += __shfl_xor(s, o);
    if (lane == 0) red[wv] = s;
    __syncthreads();
    float mu = (red[0] + red[1] + red[2] + red[3]) * (1.f / (float)CH3);
    float q = 0.f;
    for (int c = t; c < CH3; c += 256) { float d = row[c] - mu; q += d * d; }
    #pragma unroll
    for (int o = 1; o < 64; o <<= 1) q += __shfl_xor(q, o);
    if (lane == 0) red[4 + wv] = q;
    __syncthreads();
    float rstd = rsqrtf((red[4] + red[5] + red[6] + red[7]) * (1.f / (float)CH3) + 1e-5f);
    for (int c = t; c < CH3; c += 256)
        row[c] = (row[c] - mu) * rstd * olnw[c] + olnb[c];
    __syncthreads();
    int j = t & 31, slice = t >> 5;
    float a = 0.f;
    int cb = slice * (CH3 / 8);
    for (int c = cb; c < cb + CH3 / 8; ++c) a += row[c] * wout[(size_t)c * 32 + j];
    parts[slice][j] = a;
    __syncthreads();
    if (t < 32) {
        float r = bout[t];
        #pragma unroll
        for (int si = 0; si < 8; ++si) r += parts[si][t];
        outp[(size_t)g * 32 + t] = r;
    }
}

// ---------- launch ----------
extern "C" void kernel_launch(void* const* d_in, const int* in_sizes, int n_in,
                              void* d_out, int out_size, void* d_ws, size_t ws_size,
                              hipStream_t stream) {
    const float* x     = (const float*)d_in[0];
    const int*   ei    = (const int*)d_in[1];     // [2][E] int32
    const int*   batch = (const int*)d_in[2];
    const float* w_in  = (const float*)d_in[3];
    const float* b_in  = (const float*)d_in[4];
    const float* Wl    = (const float*)d_in[5];
    const float* bl    = (const float*)d_in[6];
    const float* Wr    = (const float*)d_in[7];
    const float* br    = (const float*)d_in[8];
    const float* att   = (const float*)d_in[9];
    const float* gbias = (const float*)d_in[10];
    const float* lnw   = (const float*)d_in[11];
    const float* lnb   = (const float*)d_in[12];
    const float* olnw  = (const float*)d_in[13];
    const float* olnb  = (const float*)d_in[14];
    const float* wout  = (const float*)d_in[15];
    const float* bout  = (const float*)d_in[16];

    char* ws = (char*)d_ws;
    size_t off = 0;
    auto alloc = [&](size_t bytes) -> void* {
        void* p = ws + off;
        off = (off + bytes + 255) & ~(size_t)255;
        return p;
    };
    ushort* h0     = (ushort*)alloc((size_t)N_NODES * CH * 2);
    ushort* hc     = (ushort*)alloc((size_t)N_NODES * CH3 * 2);
    ushort* xlxr   = (ushort*)alloc((size_t)N_NODES * 1536 * 2);
    ushort* wt_in  = (ushort*)alloc((size_t)CH * CH * 2);
    ushort* wt_l   = (ushort*)alloc((size_t)3 * 1536 * CH * 2);
    int*    deg    = (int*)alloc((size_t)N_NODES * 4);
    int*    rowptr = (int*)alloc((size_t)(N_NODES + 1) * 4);
    int*    cursor = (int*)alloc((size_t)N_NODES * 4);
    int*    csrc   = (int*)alloc((size_t)(N_EDGES + N_NODES) * 4);
    int*    gcount = (int*)alloc(256 * 4);
    int*    gstart = (int*)alloc(257 * 4);
    float*  pooled = (float*)alloc((size_t)NGRAPH * CH3 * 4);
    if (off > ws_size) return;

    // bf16 copy of x aliases hc (x is consumed by the h0-GEMM before hc's first write)
    ushort* xc = hc;

    // 1) convert x to bf16; all 7 weight transposes in one dispatch
    cvt_x_kernel<<<(N_NODES * CH / 4 + 255) / 256, 256, 0, stream>>>(x, xc, N_NODES * CH / 4);
    transpose_cvt_all<<<dim3(24, 24, 7), dim3(32, 8), 0, stream>>>(w_in, Wl, Wr, wt_in, wt_l);

    // 2) CSR by dst + graph segments
    int nb = (N_NODES + 255) / 256, eb = (N_EDGES + 255) / 256;
    hipMemsetAsync(deg, 0, (size_t)N_NODES * 4, stream);
    hipMemsetAsync(gcount, 0, 256 * 4, stream);
    count_both_kernel<<<eb, 256, 0, stream>>>(ei + N_EDGES, deg, N_EDGES, batch, gcount, N_NODES);
    scan_kernel<<<1, 1024, 0, stream>>>(deg, rowptr, N_NODES);
    selfloop_kernel<<<nb, 256, 0, stream>>>(rowptr, csrc, cursor, N_NODES);
    scatter_kernel<<<eb, 256, 0, stream>>>(ei, ei + N_EDGES, cursor, csrc, N_EDGES);
    gscan_kernel<<<1, 256, 0, stream>>>(gcount, gstart);

    // 3) h0 = x @ w_in + b_in  (79 row-tiles x 3 col-tiles of 256)
    gemm8_bf16_kernel<<<79 * 3, 512, 0, stream>>>(
        xc, CH, wt_in, b_in, b_in, CH, h0, CH, N_NODES, 3);

    // 4) three GATv2 layers (79 x 6 col-tiles)
    for (int l = 0; l < 3; ++l) {
        const ushort* hprev = (l == 0) ? h0 : (hc + (size_t)(l - 1) * CH);
        int ldh = (l == 0) ? CH : CH3;
        gemm8_bf16_kernel<<<79 * 6, 512, 0, stream>>>(
            hprev, ldh, wt_l + (size_t)l * 1536 * CH,
            bl + (size_t)l * CH, br + (size_t)l * CH, CH,
            xlxr, 1536, N_NODES, 6);
        gat_node_kernel<<<N_NODES / 4, 256, 0, stream>>>(
            xlxr, hprev, ldh, rowptr, csrc,
            att + (size_t)l * CH, gbias + (size_t)l * CH,
            lnw + (size_t)l * CH, lnb + (size_t)l * CH,
            hc + (size_t)l * CH, N_NODES);
    }

    // 5) pool + head (all f32, f32 output)
    pool_kernel<<<dim3(NGRAPH, CH3 / 256), 256, 0, stream>>>(hc, gstart, pooled);
    head_kernel<<<NGRAPH, 256, 0, stream>>>(pooled, olnw, olnb, wout, bout, (float*)d_out);
}